// Round 9
// baseline (174.885 us; speedup 1.0000x reference)
//
#include <hip/hip_runtime.h>
#include <hip/hip_bf16.h>

// B=8, T=1024, D=128, TEMP=0.1, WEIGHT=1.0. 56 ordered pairs (i,j), i!=j.
// All-fp8 (OCP e4m3) datapath (verified R12/R16):
//   Q,K stored *SQDS; z = dot(q',k') = 2qk*log2e/12.8
//   p' = exp2(z - 6), bias in MFMA C-init, CLAMPED to 448
//   V'' = g14*SQDS*e2, g14 = exp2(14 - |e|^2*NSCALE), elements CLAMPED +-440
//   L, sum(p*g*sp) via 5th V-block rows [g14; g14*sp] -> all-fp8 PV
//   Bias/2^14 factors cancel in nn = O/L and pred = tp/L2.
// R21: single fused kernel. Evidence: tcc floor 62us over 6 schedule variants
// (840 TF eff fp8 = 38% of ubench peak, at the known simple-structure ceiling
// with mandatory exp2 phase); MX instruction-reduction abandoned (R19/R20 NaN
// with all operand bytes <= 0x7B -> scaled-MFMA plumbing, not data). The
// remaining term: total - tcc = ~52us CONSTANT across all rounds = second
// launch + inter-kernel overhead. Fuse: grid 448x256, launch_bounds(256,2)
// -> capacity 512 >= 448, all blocks co-resident -> device-scope spin barrier
// is deadlock-free. Blocks 0-255 run one convert unit (R16 code verbatim),
// threadfence + counter; all blocks spin to 256, fence, then R16 tcc body
// verbatim. Counters zeroed via hipMemsetAsync(ws,2KB) (graph-capturable).
// Convert LDS (10KB) overlays tcc LDS (temporally disjoint).

#define T_ 1024
#define D_ 128
#define NPAIR 56
#define NSCALE 0.11271055006945026f   // (1/12.8)*log2(e)
#define SQDS 0.474785316f             // sqrt((2/12.8)*log2(e))

typedef float f32x16 __attribute__((ext_vector_type(16)));

#define B8F 131072   // bytes per batch: Q/K frags (256 chunks * 512B)
#define B8T 163840   // bytes per batch: V'' frags (320 chunks: 4 d-blocks + g-block)

__device__ __forceinline__ unsigned short f2bf(float f) {
  unsigned u = __float_as_uint(f);
  u += 0x7fff + ((u >> 16) & 1);
  return (unsigned short)(u >> 16);
}
__device__ __forceinline__ float bf2f(unsigned short v) {
  return __uint_as_float(((unsigned)v) << 16);
}
__device__ __forceinline__ float clamp8(float x) {
  return fminf(fmaxf(x, -440.f), 440.f);
}
__device__ __forceinline__ unsigned pk4(float a, float b, float c, float d) {
  int w = __builtin_amdgcn_cvt_pk_fp8_f32(a, b, 0, false);
  w = __builtin_amdgcn_cvt_pk_fp8_f32(c, d, w, true);
  return (unsigned)w;
}
__device__ __forceinline__ float waveSum(float v) {
#pragma unroll
  for (int k = 32; k >= 1; k >>= 1) v += __shfl_xor(v, k, 64);
  return v;
}
__device__ __forceinline__ void stage1k(const unsigned char* g, unsigned char* lds, int lane) {
  __builtin_amdgcn_global_load_lds(
      (const __attribute__((address_space(1))) unsigned int*)(g + lane * 16),
      (__attribute__((address_space(3))) unsigned int*)lds, 16, 0, 0);
}

// fp8 C->B transform. m[0..3] = pk4 of C-regs rg 0-3 / 4-7 / 8-11 / 12-15
// (rows 4lh+0..3, 8+4lh+.., 16+.., 24+..). Output: two 16-k B chunks (8 fp8 = i64).
__device__ __forceinline__ void c2b8(const unsigned* m, int lh, long long* b0, long long* b1) {
  unsigned send0 = lh ? m[0] : m[1];
  unsigned send1 = lh ? m[2] : m[3];
  unsigned r0 = (unsigned)__shfl_xor((int)send0, 32, 64);
  unsigned r1 = (unsigned)__shfl_xor((int)send1, 32, 64);
  union { unsigned u[2]; long long ll; } x0, x1;
  x0.u[0] = lh ? r0 : m[0];  x0.u[1] = lh ? m[1] : r0;
  x1.u[0] = lh ? r1 : m[2];  x1.u[1] = lh ? m[3] : r1;
  *b0 = x0.ll; *b1 = x1.ll;
}

#define MFMA8(A, B, C) __builtin_amdgcn_mfma_f32_32x32x16_fp8_fp8((A), (B), (C), 0, 0, 0)
#define LD8(P, Q) (*(const long long*)((P) + (Q) * 512))
#define EXPC(x) fminf(__builtin_amdgcn_exp2f(x), 448.f)
#define WAITV(N) asm volatile("s_waitcnt vmcnt(" #N ")" ::: "memory")
#define BAR() do { asm volatile("" ::: "memory"); __builtin_amdgcn_s_barrier(); asm volatile("" ::: "memory"); } while (0)

__global__ __launch_bounds__(256, 2) void fused_main(
    const float* __restrict__ embs, const int* __restrict__ fi,
    const int* __restrict__ vl, unsigned char* __restrict__ e8F,
    unsigned char* __restrict__ e8T, float* __restrict__ steps,
    float* __restrict__ loss_acc, unsigned* __restrict__ cnt,
    unsigned* __restrict__ cvt, float* __restrict__ out) {
  // tcc phase: kt 3x8192 | vt 3x10240 = 55296 B (gt overlays vt region).
  // convert phase overlays the first ~10KB (temporally disjoint).
  __shared__ unsigned char smem[55296];
  __shared__ float blred[4];
  unsigned char* kt = smem;
  unsigned char* vt = smem + 24576;
  unsigned char* gt = smem + 24576;

  const int bx = blockIdx.x;
  const int tid = threadIdx.x;

  // =================== phase A: convert (blocks 0..255) ===================
  if (bx < 256) {
    unsigned short* tileS = (unsigned short*)smem;                 // 32*136*2 = 8704 B
    float* psum = (float*)(smem + 8704);                           // 32*8*4 = 1024 B
    float* g_sh = (float*)(smem + 9728);                           // 128 B
    float* sp_sh = (float*)(smem + 9856);                          // 128 B
    const int b = bx >> 5;
    const int t0 = (bx & 31) * 32;
    const int row = tid >> 3, seg = tid & 7;

    const float* src = embs + (size_t)(b * T_ + t0 + row) * D_ + seg * 16;
    float4 g4[4];
#pragma unroll
    for (int k = 0; k < 4; k++) g4[k] = ((const float4*)src)[k];
    float s = 0.f;
    float fv[16];
#pragma unroll
    for (int k = 0; k < 4; k++) {
      s += g4[k].x * g4[k].x + g4[k].y * g4[k].y + g4[k].z * g4[k].z + g4[k].w * g4[k].w;
      fv[4 * k + 0] = g4[k].x * SQDS; fv[4 * k + 1] = g4[k].y * SQDS;
      fv[4 * k + 2] = g4[k].z * SQDS; fv[4 * k + 3] = g4[k].w * SQDS;
    }
    psum[row * 8 + seg] = s;

    // e8F store: chunk (t>>5)*8 + seg; lanes row (d lo 8) and 32+row (d hi 8)
    {
      unsigned char* dstA = e8F + (size_t)b * B8F + (size_t)((t0 >> 5) * 8 + seg) * 512;
      uint2 lo, hi;
      lo.x = pk4(fv[0], fv[1], fv[2], fv[3]);   lo.y = pk4(fv[4], fv[5], fv[6], fv[7]);
      hi.x = pk4(fv[8], fv[9], fv[10], fv[11]); hi.y = pk4(fv[12], fv[13], fv[14], fv[15]);
      *(uint2*)(dstA + row * 8) = lo;
      *(uint2*)(dstA + (size_t)(32 + row) * 8) = hi;
    }
    // bf16 tile for the transpose
#pragma unroll
    for (int k = 0; k < 16; k++) tileS[row * 136 + seg * 16 + k] = f2bf(fv[k]);
    __syncthreads();

    if (tid < 32) {
      float t = 0.f;
#pragma unroll
      for (int k = 0; k < 8; k++) t += psum[tid * 8 + k];
      int gr = b * T_ + t0 + tid;
      float sp = (float)fi[gr] / (float)vl[b];
      steps[gr] = sp;
      sp_sh[tid] = sp;
      g_sh[tid] = __builtin_amdgcn_exp2f(14.0f - t * NSCALE);   // g14
    }
    __syncthreads();

    // e8T d-blocks 0..3: V'' = g14 * (SQDS*e), transposed, clamped
    {
      const int c8 = tid >> 5;
      const int n2 = c8 & 3, scp = c8 >> 2;
      const int dd = n2 * 32 + (tid & 31);
#pragma unroll
      for (int half = 0; half < 2; half++) {
        const int lane = half * 32 + (tid & 31);
        const int sl = scp * 16 + half * 8;
        float vv[8];
#pragma unroll
        for (int jj = 0; jj < 8; jj++)
          vv[jj] = clamp8(bf2f(tileS[(sl + jj) * 136 + dd]) * g_sh[sl + jj]);
        uint2 wv;
        wv.x = pk4(vv[0], vv[1], vv[2], vv[3]);
        wv.y = pk4(vv[4], vv[5], vv[6], vv[7]);
        int c = n2 * 64 + (t0 >> 4) + scp;
        *(uint2*)(e8T + (size_t)b * B8T + (size_t)c * 512 + lane * 8) = wv;
      }
    }
    // e8T g-block (n2=4): row m=0 -> g14, m=1 -> g14*sp, else 0
    if (tid < 128) {
      const int sc2 = tid >> 6, lane = tid & 63;
      const int m = lane & 31, kh = lane >> 5;
      uint2 wv; wv.x = 0u; wv.y = 0u;
      if (m < 2) {
        float vv[8];
#pragma unroll
        for (int e = 0; e < 8; e++) {
          int sl = sc2 * 16 + kh * 8 + e;
          float gg = g_sh[sl];
          vv[e] = clamp8(m ? gg * sp_sh[sl] : gg);
        }
        wv.x = pk4(vv[0], vv[1], vv[2], vv[3]);
        wv.y = pk4(vv[4], vv[5], vv[6], vv[7]);
      }
      int c = 256 + (t0 >> 4) + sc2;
      *(uint2*)(e8T + (size_t)b * B8T + (size_t)c * 512 + lane * 8) = wv;
    }
    // release: data visible before the counter increment
    __syncthreads();
    __threadfence();
    if (tid == 0) atomicAdd(cvt, 1u);
  }

  // =================== device-wide convert barrier ===================
  // All 448 blocks co-resident (capacity 512 at 2 blocks/CU) -> spin is safe.
  if (tid == 0) {
    while (atomicAdd(cvt, 0u) < 256u) __builtin_amdgcn_s_sleep(2);
  }
  __syncthreads();
  __threadfence();   // acquire: converted data visible to all threads

  // =================== phase B: tcc (R16 body, verbatim) ===================
  const int pair = bx >> 3;
  const int tile = bx & 7;
  const int i = pair / 7;
  const int r = pair % 7;
  const int j = r + (r >= i ? 1 : 0);
  const int w = tid >> 6;
  const int l = tid & 63;
  const int l31 = l & 31;
  const int lh = l >> 5;
  const int tb = tile * 128 + w * 32;

  const unsigned char* eFi = e8F + (size_t)i * B8F;
  const unsigned char* eFj = e8F + (size_t)j * B8F;
  const unsigned char* eTj = e8T + (size_t)j * B8T;
  const unsigned char* eTi = e8T + (size_t)i * B8T;

  // Q fp8 B-operand chunks (n=t, k=d)
  long long qf8[8];
  {
    const unsigned char* qb = eFi + (size_t)((tb >> 5) * 8) * 512 + l * 8;
#pragma unroll
    for (int kc = 0; kc < 8; kc++) qf8[kc] = LD8(qb, kc);
  }

  const f32x16 Z = {0.f, 0.f, 0.f, 0.f, 0.f, 0.f, 0.f, 0.f,
                    0.f, 0.f, 0.f, 0.f, 0.f, 0.f, 0.f, 0.f};
  const f32x16 CM6 = {-6.f, -6.f, -6.f, -6.f, -6.f, -6.f, -6.f, -6.f,
                      -6.f, -6.f, -6.f, -6.f, -6.f, -6.f, -6.f, -6.f};
  f32x16 o[5];   // o[0..3]=O^T d-blocks, o[4]=g-block (row0=L')
#pragma unroll
  for (int n2 = 0; n2 < 5; n2++) o[n2] = Z;

  auto stageP1 = [&](int t, int b) {
    stage1k(eFj + (size_t)(8 * t + 2 * w) * 1024, kt + b * 8192 + (2 * w) * 1024, l);
    stage1k(eFj + (size_t)(8 * t + 2 * w + 1) * 1024, kt + b * 8192 + (2 * w + 1) * 1024, l);
#pragma unroll
    for (int u = 0; u < 3; u++) {
      int vu = w + 4 * u;
      if (vu < 10) {
        int n2v = vu >> 1, uh = vu & 1;
        stage1k(eTj + (size_t)(n2v * 32 + t * 2 + uh) * 1024, vt + b * 10240 + vu * 1024, l);
      }
    }
  };
  auto stageP2 = [&](int t, int b) {
    stage1k(eFi + (size_t)(8 * t + 2 * w) * 1024, kt + b * 8192 + (2 * w) * 1024, l);
    stage1k(eFi + (size_t)(8 * t + 2 * w + 1) * 1024, kt + b * 8192 + (2 * w + 1) * 1024, l);
    if (w < 2) stage1k(eTi + (size_t)(128 + t * 2 + w) * 1024, gt + b * 2048 + w * 1024, l);
  };

  // ---------------- phase 1: s-tile 64, 16 iters, QK one tile ahead ----------------
  stageP1(0, 0);
  stageP1(1, 1);
  WAITV(0);
  BAR();

  f32x16 ca0, ca1;
  {  // prologue QK(0) from buf0
    const unsigned char* kb = kt + l * 8;
    ca0 = MFMA8(LD8(kb, 0), qf8[0], CM6);
    ca1 = MFMA8(LD8(kb, 8), qf8[0], CM6);
#pragma unroll
    for (int dc = 1; dc < 8; dc++) {
      ca0 = MFMA8(LD8(kb, dc), qf8[dc], ca0);
      ca1 = MFMA8(LD8(kb, 8 + dc), qf8[dc], ca1);
    }
  }

  {
    int cur = 0, nxt = 1, pre = 2;
    for (int st = 0; st < 16; st++) {
      if (st <= 13) stageP1(st + 2, pre);
      __builtin_amdgcn_sched_barrier(0);

      f32x16 cb0, cb1;
      if (st < 15) {
        const unsigned char* kb = kt + nxt * 8192 + l * 8;
        cb0 = MFMA8(LD8(kb, 0), qf8[0], CM6);
        cb1 = MFMA8(LD8(kb, 8), qf8[0], CM6);
#pragma unroll
        for (int dc = 1; dc < 8; dc++) {
          cb0 = MFMA8(LD8(kb, dc), qf8[dc], cb0);
          cb1 = MFMA8(LD8(kb, 8 + dc), qf8[dc], cb1);
        }
      }

      unsigned m0[4], m1[4];
#pragma unroll
      for (int k2 = 0; k2 < 4; k2++) {
        m0[k2] = pk4(EXPC(ca0[4 * k2]), EXPC(ca0[4 * k2 + 1]),
                     EXPC(ca0[4 * k2 + 2]), EXPC(ca0[4 * k2 + 3]));
        m1[k2] = pk4(EXPC(ca1[4 * k2]), EXPC(ca1[4 * k2 + 1]),
                     EXPC(ca1[4 * k2 + 2]), EXPC(ca1[4 * k2 + 3]));
      }
      long long pB[4];
      c2b8(m0, lh, &pB[0], &pB[1]);
      c2b8(m1, lh, &pB[2], &pB[3]);

      const unsigned char* vb = vt + cur * 10240 + l * 8;
#pragma unroll
      for (int n2 = 0; n2 < 5; n2++)
#pragma unroll
        for (int sc = 0; sc < 4; sc++)
          o[n2] = MFMA8(LD8(vb, n2 * 4 + sc), pB[sc], o[n2]);

      if (st <= 13) {
        WAITV(0);
        BAR();
      } else if (st == 15) {
        BAR();
      }
      if (st < 15) { ca0 = cb0; ca1 = cb1; }
      int tswap = cur; cur = nxt; nxt = pre; pre = tswap;
    }
  }

  // stage phase-2 tiles 0,1 (loads fly under the interphase VALU)
  stageP2(0, 0);
  stageP2(1, 1);

  // ---- interphase: nn^T = O^T / L'; fp8 B-frags via shfl ----
  float Lme = o[4][0];
  float Lo = __shfl_xor(Lme, 32, 64);
  float inv = 1.0f / (lh ? Lo : Lme);
  long long qf2[8];
#pragma unroll
  for (int n2 = 0; n2 < 4; n2++) {
    unsigned mm[4];
#pragma unroll
    for (int k2 = 0; k2 < 4; k2++)
      mm[k2] = pk4(o[n2][4 * k2] * inv, o[n2][4 * k2 + 1] * inv,
                   o[n2][4 * k2 + 2] * inv, o[n2][4 * k2 + 3] * inv);
    c2b8(mm, lh, &qf2[2 * n2], &qf2[2 * n2 + 1]);
  }
  f32x16 acc6 = Z;
  WAITV(0);
  BAR();

  f32x16 da0, da1;
  {  // prologue QK2(0) from buf0
    const unsigned char* kb = kt + l * 8;
    da0 = MFMA8(LD8(kb, 0), qf2[0], CM6);
    da1 = MFMA8(LD8(kb, 8), qf2[0], CM6);
#pragma unroll
    for (int dc = 1; dc < 8; dc++) {
      da0 = MFMA8(LD8(kb, dc), qf2[dc], da0);
      da1 = MFMA8(LD8(kb, 8 + dc), qf2[dc], da1);
    }
  }

  // ---------------- phase 2: s-tile 64, 16 iters, K + g-block ----------------
  {
    int cur = 0, nxt = 1, pre = 2;
    for (int st = 0; st < 16; st++) {
      if (st <= 13) stageP2(st + 2, pre);
      __builtin_amdgcn_sched_barrier(0);

      f32x16 db0, db1;
      if (st < 15) {
        const unsigned char* kb = kt + nxt * 8192 + l * 8;
        db0 = MFMA8(LD8(kb, 0), qf2[0], CM6);
        db1 = MFMA8(LD8(kb, 8), qf2[0], CM6);
#pragma unroll
        for (int dc = 1; dc < 8; dc++) {
          db0 = MFMA8(LD8(kb, dc), qf2[dc], db0);
          db1 = MFMA8(LD8(kb, 8 + dc), qf2[dc], db1);
        }
      }

      unsigned m0[4], m1[4];
#pragma unroll
      for (int k2 = 0; k2 < 4; k2++) {
        m0[k2] = pk4(EXPC(da0[4 * k2]), EXPC(da0[4 * k2 + 1]),
                     EXPC(da0[4 * k2 + 2]), EXPC(da0[4 * k2 + 3]));
        m1[k2] = pk4(EXPC(da1[4 * k2]), EXPC(da1[4 * k2 + 1]),
                     EXPC(da1[4 * k2 + 2]), EXPC(da1[4 * k2 + 3]));
      }
      long long pB[4];
      c2b8(m0, lh, &pB[0], &pB[1]);
      c2b8(m1, lh, &pB[2], &pB[3]);

      const unsigned char* gb = gt + cur * 2048 + l * 8;
#pragma unroll
      for (int sc = 0; sc < 4; sc++)
        acc6 = MFMA8(LD8(gb, sc), pB[sc], acc6);

      if (st <= 13) {
        WAITV(0);
        BAR();
      }
      if (st < 15) { da0 = db0; da1 = db1; }
      int tswap = cur; cur = nxt; nxt = pre; pre = tswap;
    }
  }

  // ---- epilogue: pred = tp/L2 (rows 0,1 at lh=0), MSE, fused finalize ----
  float local = 0.f;
  if (lh == 0) {
    float pred = acc6[1] / acc6[0];
    float tt = steps[i * T_ + tb + l31];
    float dd = pred - tt;
    local = dd * dd;
  }
  local = waveSum(local);
  if (l == 0) blred[w] = local;
  __syncthreads();
  if (tid == 0) {
    atomicAdd(loss_acc, blred[0] + blred[1] + blred[2] + blred[3]);
    __threadfence();
    unsigned old = atomicAdd(cnt, 1u);
    if (old == (unsigned)(gridDim.x - 1)) {
      float v = atomicAdd(loss_acc, 0.0f);
      out[0] = v * (1.0f / (float)(NPAIR * T_));
    }
  }
}

extern "C" void kernel_launch(void* const* d_in, const int* in_sizes, int n_in,
                              void* d_out, int out_size, void* d_ws, size_t ws_size,
                              hipStream_t stream) {
  const float* embs = (const float*)d_in[0];
  const int* frame_idxs = (const int*)d_in[1];
  const int* video_len = (const int*)d_in[2];
  float* out = (float*)d_out;

  char* ws = (char*)d_ws;
  float* acc = (float*)ws;                                  // @0
  unsigned* cnt = (unsigned*)(ws + 512);                    // @512
  unsigned* cvt = (unsigned*)(ws + 1024);                   // @1024
  float* steps = (float*)(ws + 4096);                       // 8192 f32
  unsigned char* e8F = (unsigned char*)(ws + 65536);        // 1 MB
  unsigned char* e8T = e8F + (size_t)8 * B8F;               // 1.25 MB

  // zero acc/cnt/cvt each replay (graph-capturable async memset)
  hipMemsetAsync(ws, 0, 2048, stream);

  fused_main<<<dim3(NPAIR * 8), dim3(256), 0, stream>>>(
      embs, frame_idxs, video_len, e8F, e8T, steps, acc, cnt, cvt, out);
}

// Round 10
// 114.022 us; speedup vs baseline: 1.5338x; 1.5338x over previous
//
#include <hip/hip_runtime.h>
#include <hip/hip_bf16.h>

// B=8, T=1024, D=128, TEMP=0.1, WEIGHT=1.0. 56 ordered pairs (i,j), i!=j.
// All-fp8 (OCP e4m3) datapath (verified R12/R16):
//   Q,K stored *SQDS; z = dot(q',k') = 2qk*log2e/12.8
//   p' = exp2(z - 6), bias in MFMA C-init, CLAMPED to 448
//   V'' = g14*SQDS*e2, g14 = exp2(14 - |e|^2*NSCALE), elements CLAMPED +-440
//   L, sum(p*g*sp) via 5th V-block rows [g14; g14*sp] -> all-fp8 PV
//   Bias/2^14 factors cancel in nn = O/L and pred = tp/L2.
// R22: R16 base (best: 61.8us kernel / 114.44 total) + cross-block de-phase
// stagger. Evidence: R21 proved the ~50us total-kernel gap is harness-fixed
// (persists with ONE launch), so only tcc's 62us is improvable. Pipe-demand
// arithmetic says 2 waves/SIMD (from two DIFFERENT blocks) could run in
// ~28us if anti-phased; they are phase-LOCKED (simultaneous start, identical
// deterministic code, barrier cadence) so QK contends with QK and convert
// with convert -- why R13/R16/R18 were all null. Fix: delay the second
// co-resident block (bx>=256; CU c hosts c and c+256) by s_sleep(28)~1792cy
// (~1/3 iteration) so one block's convert runs under the other's MFMA.
// Null result => declare structural roofline.

#define T_ 1024
#define D_ 128
#define NPAIR 56
#define NSCALE 0.11271055006945026f   // (1/12.8)*log2(e)
#define SQDS 0.474785316f             // sqrt((2/12.8)*log2(e))

typedef float f32x16 __attribute__((ext_vector_type(16)));

#define B8F 131072   // bytes per batch: Q/K frags (256 chunks * 512B)
#define B8T 163840   // bytes per batch: V'' frags (320 chunks: 4 d-blocks + g-block)

__device__ __forceinline__ unsigned short f2bf(float f) {
  unsigned u = __float_as_uint(f);
  u += 0x7fff + ((u >> 16) & 1);
  return (unsigned short)(u >> 16);
}
__device__ __forceinline__ float bf2f(unsigned short v) {
  return __uint_as_float(((unsigned)v) << 16);
}
__device__ __forceinline__ float clamp8(float x) {
  return fminf(fmaxf(x, -440.f), 440.f);
}
__device__ __forceinline__ unsigned pk4(float a, float b, float c, float d) {
  int w = __builtin_amdgcn_cvt_pk_fp8_f32(a, b, 0, false);
  w = __builtin_amdgcn_cvt_pk_fp8_f32(c, d, w, true);
  return (unsigned)w;
}
__device__ __forceinline__ float waveSum(float v) {
#pragma unroll
  for (int k = 32; k >= 1; k >>= 1) v += __shfl_xor(v, k, 64);
  return v;
}
__device__ __forceinline__ void stage1k(const unsigned char* g, unsigned char* lds, int lane) {
  __builtin_amdgcn_global_load_lds(
      (const __attribute__((address_space(1))) unsigned int*)(g + lane * 16),
      (__attribute__((address_space(3))) unsigned int*)lds, 16, 0, 0);
}

// fp8 C->B transform. m[0..3] = pk4 of C-regs rg 0-3 / 4-7 / 8-11 / 12-15
// (rows 4lh+0..3, 8+4lh+.., 16+.., 24+..). Output: two 16-k B chunks (8 fp8 = i64).
__device__ __forceinline__ void c2b8(const unsigned* m, int lh, long long* b0, long long* b1) {
  unsigned send0 = lh ? m[0] : m[1];
  unsigned send1 = lh ? m[2] : m[3];
  unsigned r0 = (unsigned)__shfl_xor((int)send0, 32, 64);
  unsigned r1 = (unsigned)__shfl_xor((int)send1, 32, 64);
  union { unsigned u[2]; long long ll; } x0, x1;
  x0.u[0] = lh ? r0 : m[0];  x0.u[1] = lh ? m[1] : r0;
  x1.u[0] = lh ? r1 : m[2];  x1.u[1] = lh ? m[3] : r1;
  *b0 = x0.ll; *b1 = x1.ll;
}

#define MFMA8(A, B, C) __builtin_amdgcn_mfma_f32_32x32x16_fp8_fp8((A), (B), (C), 0, 0, 0)
#define LD8(P, Q) (*(const long long*)((P) + (Q) * 512))
#define EXPC(x) fminf(__builtin_amdgcn_exp2f(x), 448.f)
#define WAITV(N) asm volatile("s_waitcnt vmcnt(" #N ")" ::: "memory")
#define BAR() do { asm volatile("" ::: "memory"); __builtin_amdgcn_s_barrier(); asm volatile("" ::: "memory"); } while (0)

// ---- convert: fp32 -> fp8 frag buffers + steps + ws init ----
__global__ __launch_bounds__(256) void convert_kernel(
    const float* __restrict__ embs, const int* __restrict__ fi,
    const int* __restrict__ vl, unsigned char* __restrict__ e8F,
    unsigned char* __restrict__ e8T, float* __restrict__ steps,
    float* __restrict__ acc, unsigned* __restrict__ cnt) {
  __shared__ unsigned short tileS[32 * 136];
  __shared__ float psum[32][8];
  __shared__ float g_sh[32], sp_sh[32];
  const int b = blockIdx.x >> 5;
  const int t0 = (blockIdx.x & 31) * 32;
  const int tid = threadIdx.x;
  const int row = tid >> 3, seg = tid & 7;

  if (blockIdx.x == 0 && tid == 0) { acc[0] = 0.f; cnt[0] = 0u; }

  const float* src = embs + (size_t)(b * T_ + t0 + row) * D_ + seg * 16;
  float4 g4[4];
#pragma unroll
  for (int k = 0; k < 4; k++) g4[k] = ((const float4*)src)[k];
  float s = 0.f;
  float fv[16];
#pragma unroll
  for (int k = 0; k < 4; k++) {
    s += g4[k].x * g4[k].x + g4[k].y * g4[k].y + g4[k].z * g4[k].z + g4[k].w * g4[k].w;
    fv[4 * k + 0] = g4[k].x * SQDS; fv[4 * k + 1] = g4[k].y * SQDS;
    fv[4 * k + 2] = g4[k].z * SQDS; fv[4 * k + 3] = g4[k].w * SQDS;
  }
  psum[row][seg] = s;

  // e8F store: chunk (t>>5)*8 + seg; lanes row (d lo 8) and 32+row (d hi 8)
  {
    unsigned char* dstA = e8F + (size_t)b * B8F + (size_t)((t0 >> 5) * 8 + seg) * 512;
    uint2 lo, hi;
    lo.x = pk4(fv[0], fv[1], fv[2], fv[3]);   lo.y = pk4(fv[4], fv[5], fv[6], fv[7]);
    hi.x = pk4(fv[8], fv[9], fv[10], fv[11]); hi.y = pk4(fv[12], fv[13], fv[14], fv[15]);
    *(uint2*)(dstA + row * 8) = lo;
    *(uint2*)(dstA + (size_t)(32 + row) * 8) = hi;
  }
  // bf16 tile for the transpose
#pragma unroll
  for (int k = 0; k < 16; k++) tileS[row * 136 + seg * 16 + k] = f2bf(fv[k]);
  __syncthreads();

  if (tid < 32) {
    float t = 0.f;
#pragma unroll
    for (int k = 0; k < 8; k++) t += psum[tid][k];
    int gr = b * T_ + t0 + tid;
    float sp = (float)fi[gr] / (float)vl[b];
    steps[gr] = sp;
    sp_sh[tid] = sp;
    g_sh[tid] = __builtin_amdgcn_exp2f(14.0f - t * NSCALE);   // g14
  }
  __syncthreads();

  // e8T d-blocks 0..3: V'' = g14 * (SQDS*e), transposed, clamped to fp8 range
  {
    const int c8 = tid >> 5;
    const int n2 = c8 & 3, scp = c8 >> 2;
    const int dd = n2 * 32 + (tid & 31);
#pragma unroll
    for (int half = 0; half < 2; half++) {
      const int lane = half * 32 + (tid & 31);
      const int sl = scp * 16 + half * 8;
      float vv[8];
#pragma unroll
      for (int jj = 0; jj < 8; jj++)
        vv[jj] = clamp8(bf2f(tileS[(sl + jj) * 136 + dd]) * g_sh[sl + jj]);
      uint2 wv;
      wv.x = pk4(vv[0], vv[1], vv[2], vv[3]);
      wv.y = pk4(vv[4], vv[5], vv[6], vv[7]);
      int c = n2 * 64 + (t0 >> 4) + scp;
      *(uint2*)(e8T + (size_t)b * B8T + (size_t)c * 512 + lane * 8) = wv;
    }
  }
  // e8T g-block (n2=4): row m=0 -> g14, m=1 -> g14*sp, else 0 (clamped)
  if (tid < 128) {
    const int sc2 = tid >> 6, lane = tid & 63;
    const int m = lane & 31, kh = lane >> 5;
    uint2 wv; wv.x = 0u; wv.y = 0u;
    if (m < 2) {
      float vv[8];
#pragma unroll
      for (int e = 0; e < 8; e++) {
        int sl = sc2 * 16 + kh * 8 + e;
        float gg = g_sh[sl];
        vv[e] = clamp8(m ? gg * sp_sh[sl] : gg);
      }
      wv.x = pk4(vv[0], vv[1], vv[2], vv[3]);
      wv.y = pk4(vv[4], vv[5], vv[6], vv[7]);
    }
    int c = 256 + (t0 >> 4) + sc2;
    *(uint2*)(e8T + (size_t)b * B8T + (size_t)c * 512 + lane * 8) = wv;
  }
}

__global__ __launch_bounds__(256, 2) void tcc_main(
    const unsigned char* __restrict__ e8F, const unsigned char* __restrict__ e8T,
    const float* __restrict__ steps, float* __restrict__ loss_acc,
    unsigned* __restrict__ cnt, float* __restrict__ out) {
  // Triple-buffered: kt 3x8192 | vt 3x10240 = 55296 B.
  // Phase 2 reuses vt's region for gt (3x2048).
  __shared__ unsigned char smem[55296];
  __shared__ float blred[4];
  unsigned char* kt = smem;
  unsigned char* vt = smem + 24576;
  unsigned char* gt = smem + 24576;

  const int bx = blockIdx.x;

  // De-phase the second co-resident block on each CU (CU c hosts bx=c and
  // bx=c+256): ~1792cy =~ 1/3 iteration, so its VALU/convert phase runs
  // under the partner block's MFMA phase instead of contending.
  if (bx >= 256) __builtin_amdgcn_s_sleep(28);

  const int pair = bx >> 3;
  const int tile = bx & 7;
  const int i = pair / 7;
  const int r = pair % 7;
  const int j = r + (r >= i ? 1 : 0);
  const int tid = threadIdx.x;
  const int w = tid >> 6;
  const int l = tid & 63;
  const int l31 = l & 31;
  const int lh = l >> 5;
  const int tb = tile * 128 + w * 32;

  const unsigned char* eFi = e8F + (size_t)i * B8F;
  const unsigned char* eFj = e8F + (size_t)j * B8F;
  const unsigned char* eTj = e8T + (size_t)j * B8T;
  const unsigned char* eTi = e8T + (size_t)i * B8T;

  // Q fp8 B-operand chunks (n=t, k=d)
  long long qf8[8];
  {
    const unsigned char* qb = eFi + (size_t)((tb >> 5) * 8) * 512 + l * 8;
#pragma unroll
    for (int kc = 0; kc < 8; kc++) qf8[kc] = LD8(qb, kc);
  }

  const f32x16 Z = {0.f, 0.f, 0.f, 0.f, 0.f, 0.f, 0.f, 0.f,
                    0.f, 0.f, 0.f, 0.f, 0.f, 0.f, 0.f, 0.f};
  const f32x16 CM6 = {-6.f, -6.f, -6.f, -6.f, -6.f, -6.f, -6.f, -6.f,
                      -6.f, -6.f, -6.f, -6.f, -6.f, -6.f, -6.f, -6.f};
  f32x16 o[5];   // o[0..3]=O^T d-blocks, o[4]=g-block (row0=L')
#pragma unroll
  for (int n2 = 0; n2 < 5; n2++) o[n2] = Z;

  // stage phase-1 tile t into buffer b: wave w does K units 2w,2w+1;
  // V units w, w+4, (w<2: 8+w).
  auto stageP1 = [&](int t, int b) {
    stage1k(eFj + (size_t)(8 * t + 2 * w) * 1024, kt + b * 8192 + (2 * w) * 1024, l);
    stage1k(eFj + (size_t)(8 * t + 2 * w + 1) * 1024, kt + b * 8192 + (2 * w + 1) * 1024, l);
#pragma unroll
    for (int u = 0; u < 3; u++) {
      int vu = w + 4 * u;
      if (vu < 10) {
        int n2v = vu >> 1, uh = vu & 1;
        stage1k(eTj + (size_t)(n2v * 32 + t * 2 + uh) * 1024, vt + b * 10240 + vu * 1024, l);
      }
    }
  };
  // stage phase-2 tile t into buffer b: K units 2w,2w+1; g unit w for w<2.
  auto stageP2 = [&](int t, int b) {
    stage1k(eFi + (size_t)(8 * t + 2 * w) * 1024, kt + b * 8192 + (2 * w) * 1024, l);
    stage1k(eFi + (size_t)(8 * t + 2 * w + 1) * 1024, kt + b * 8192 + (2 * w + 1) * 1024, l);
    if (w < 2) stage1k(eTi + (size_t)(128 + t * 2 + w) * 1024, gt + b * 2048 + w * 1024, l);
  };

  // ---------------- phase 1: s-tile 64, 16 iters, QK one tile ahead ----------------
  stageP1(0, 0);
  stageP1(1, 1);
  WAITV(0);
  BAR();

  f32x16 ca0, ca1;
  {  // prologue QK(0) from buf0
    const unsigned char* kb = kt + l * 8;
    ca0 = MFMA8(LD8(kb, 0), qf8[0], CM6);
    ca1 = MFMA8(LD8(kb, 8), qf8[0], CM6);
#pragma unroll
    for (int dc = 1; dc < 8; dc++) {
      ca0 = MFMA8(LD8(kb, dc), qf8[dc], ca0);
      ca1 = MFMA8(LD8(kb, 8 + dc), qf8[dc], ca1);
    }
  }

  {
    int cur = 0, nxt = 1, pre = 2;
    for (int st = 0; st < 16; st++) {
      if (st <= 13) stageP1(st + 2, pre);
      __builtin_amdgcn_sched_barrier(0);

      // QK(st+1) from the next buffer -- independent of this iter's convert;
      // the scheduler interleaves these MFMAs with the VALU below.
      f32x16 cb0, cb1;
      if (st < 15) {
        const unsigned char* kb = kt + nxt * 8192 + l * 8;
        cb0 = MFMA8(LD8(kb, 0), qf8[0], CM6);
        cb1 = MFMA8(LD8(kb, 8), qf8[0], CM6);
#pragma unroll
        for (int dc = 1; dc < 8; dc++) {
          cb0 = MFMA8(LD8(kb, dc), qf8[dc], cb0);
          cb1 = MFMA8(LD8(kb, 8 + dc), qf8[dc], cb1);
        }
      }

      // convert ca(st) -> fp8 P-fragments
      unsigned m0[4], m1[4];
#pragma unroll
      for (int k2 = 0; k2 < 4; k2++) {
        m0[k2] = pk4(EXPC(ca0[4 * k2]), EXPC(ca0[4 * k2 + 1]),
                     EXPC(ca0[4 * k2 + 2]), EXPC(ca0[4 * k2 + 3]));
        m1[k2] = pk4(EXPC(ca1[4 * k2]), EXPC(ca1[4 * k2 + 1]),
                     EXPC(ca1[4 * k2 + 2]), EXPC(ca1[4 * k2 + 3]));
      }
      long long pB[4];
      c2b8(m0, lh, &pB[0], &pB[1]);
      c2b8(m1, lh, &pB[2], &pB[3]);

      const unsigned char* vb = vt + cur * 10240 + l * 8;
#pragma unroll
      for (int n2 = 0; n2 < 5; n2++)
#pragma unroll
        for (int sc = 0; sc < 4; sc++)
          o[n2] = MFMA8(LD8(vb, n2 * 4 + sc), pB[sc], o[n2]);

      if (st <= 13) {
        WAITV(0);   // stage(st+2) landed (issued a full iteration ago)
        BAR();
      } else if (st == 15) {
        BAR();      // before phase-2 staging overwrites buffers
      }
      if (st < 15) { ca0 = cb0; ca1 = cb1; }
      int tswap = cur; cur = nxt; nxt = pre; pre = tswap;
    }
  }

  // stage phase-2 tiles 0,1 (loads fly under the interphase VALU)
  stageP2(0, 0);
  stageP2(1, 1);

  // ---- interphase: nn^T = O^T / L'; fp8 B-frags via shfl ----
  float Lme = o[4][0];
  float Lo = __shfl_xor(Lme, 32, 64);
  float inv = 1.0f / (lh ? Lo : Lme);
  long long qf2[8];
#pragma unroll
  for (int n2 = 0; n2 < 4; n2++) {
    unsigned mm[4];
#pragma unroll
    for (int k2 = 0; k2 < 4; k2++)
      mm[k2] = pk4(o[n2][4 * k2] * inv, o[n2][4 * k2 + 1] * inv,
                   o[n2][4 * k2 + 2] * inv, o[n2][4 * k2 + 3] * inv);
    c2b8(mm, lh, &qf2[2 * n2], &qf2[2 * n2 + 1]);
  }
  f32x16 acc6 = Z;
  WAITV(0);
  BAR();

  f32x16 da0, da1;
  {  // prologue QK2(0) from buf0
    const unsigned char* kb = kt + l * 8;
    da0 = MFMA8(LD8(kb, 0), qf2[0], CM6);
    da1 = MFMA8(LD8(kb, 8), qf2[0], CM6);
#pragma unroll
    for (int dc = 1; dc < 8; dc++) {
      da0 = MFMA8(LD8(kb, dc), qf2[dc], da0);
      da1 = MFMA8(LD8(kb, 8 + dc), qf2[dc], da1);
    }
  }

  // ---------------- phase 2: s-tile 64, 16 iters, K + g-block ----------------
  {
    int cur = 0, nxt = 1, pre = 2;
    for (int st = 0; st < 16; st++) {
      if (st <= 13) stageP2(st + 2, pre);
      __builtin_amdgcn_sched_barrier(0);

      f32x16 db0, db1;
      if (st < 15) {
        const unsigned char* kb = kt + nxt * 8192 + l * 8;
        db0 = MFMA8(LD8(kb, 0), qf2[0], CM6);
        db1 = MFMA8(LD8(kb, 8), qf2[0], CM6);
#pragma unroll
        for (int dc = 1; dc < 8; dc++) {
          db0 = MFMA8(LD8(kb, dc), qf2[dc], db0);
          db1 = MFMA8(LD8(kb, 8 + dc), qf2[dc], db1);
        }
      }

      unsigned m0[4], m1[4];
#pragma unroll
      for (int k2 = 0; k2 < 4; k2++) {
        m0[k2] = pk4(EXPC(da0[4 * k2]), EXPC(da0[4 * k2 + 1]),
                     EXPC(da0[4 * k2 + 2]), EXPC(da0[4 * k2 + 3]));
        m1[k2] = pk4(EXPC(da1[4 * k2]), EXPC(da1[4 * k2 + 1]),
                     EXPC(da1[4 * k2 + 2]), EXPC(da1[4 * k2 + 3]));
      }
      long long pB[4];
      c2b8(m0, lh, &pB[0], &pB[1]);
      c2b8(m1, lh, &pB[2], &pB[3]);

      const unsigned char* gb = gt + cur * 2048 + l * 8;
#pragma unroll
      for (int sc = 0; sc < 4; sc++)
        acc6 = MFMA8(LD8(gb, sc), pB[sc], acc6);

      if (st <= 13) {
        WAITV(0);
        BAR();
      }
      if (st < 15) { da0 = db0; da1 = db1; }
      int tswap = cur; cur = nxt; nxt = pre; pre = tswap;
    }
  }

  // ---- epilogue: pred = tp/L2 (rows 0,1 at lh=0), MSE, fused finalize ----
  float local = 0.f;
  if (lh == 0) {
    float pred = acc6[1] / acc6[0];
    float tt = steps[i * T_ + tb + l31];
    float dd = pred - tt;
    local = dd * dd;
  }
  local = waveSum(local);
  if (l == 0) blred[w] = local;
  __syncthreads();
  if (tid == 0) {
    atomicAdd(loss_acc, blred[0] + blred[1] + blred[2] + blred[3]);
    __threadfence();
    unsigned old = atomicAdd(cnt, 1u);
    if (old == (unsigned)(gridDim.x - 1)) {
      float v = atomicAdd(loss_acc, 0.0f);
      out[0] = v * (1.0f / (float)(NPAIR * T_));
    }
  }
}

extern "C" void kernel_launch(void* const* d_in, const int* in_sizes, int n_in,
                              void* d_out, int out_size, void* d_ws, size_t ws_size,
                              hipStream_t stream) {
  const float* embs = (const float*)d_in[0];
  const int* frame_idxs = (const int*)d_in[1];
  const int* video_len = (const int*)d_in[2];
  float* out = (float*)d_out;

  char* ws = (char*)d_ws;
  float* acc = (float*)ws;                                  // @0
  unsigned* cnt = (unsigned*)(ws + 512);                    // @512
  float* steps = (float*)(ws + 4096);                       // 8192 f32
  unsigned char* e8F = (unsigned char*)(ws + 65536);        // 1 MB
  unsigned char* e8T = e8F + (size_t)8 * B8F;               // 1.25 MB

  convert_kernel<<<dim3(256), dim3(256), 0, stream>>>(embs, frame_idxs, video_len,
                                                      e8F, e8T, steps, acc, cnt);
  tcc_main<<<dim3(NPAIR * 8), dim3(256), 0, stream>>>(e8F, e8T, steps, acc, cnt, out);
}